// Round 1
// baseline (408.848 us; speedup 1.0000x reference)
//
#include <hip/hip_runtime.h>
#include <hip/hip_bf16.h>
#include <math.h>

// Problem constants (reference: B=64, T=2048, D=256)
#define PB 64
#define PT 2048
#define PD 256
#define PM (PB * PT)          // 131072 rows of the scores GEMM

// ---------------- Kernel A: scores = attn . tanh(xs @ W^T + b) -------------
// GEMM M=131072, N=256 (reduced in epilogue), K=256. fp32 vector FMA.
// Tile: BM=128 rows, e handled in 2 chunks of 128, BK=64. 256 threads,
// 8x8 register tile per thread.
#define BM 128
#define BKC 64
#define LDA 132               // BM + 4 pad: breaks bank conflicts, keeps 16B align

__global__ __launch_bounds__(256) void score_kernel(
    const float* __restrict__ xs, const float* __restrict__ W,
    const float* __restrict__ bias, const float* __restrict__ attn,
    float* __restrict__ scores)
{
    __shared__ float As[BKC][LDA];
    __shared__ float Ws[BKC][LDA];

    const int tid = threadIdx.x;
    const int tx  = tid & 15;       // e direction (8 cols each)
    const int ty  = tid >> 4;       // m direction (8 rows each)
    const int bm  = blockIdx.x * BM;
    const int kq  = tid & 15;       // staging: float4 index along k
    const int r0  = tid >> 4;       // staging: row base

    float spart[8];
#pragma unroll
    for (int i = 0; i < 8; ++i) spart[i] = 0.f;

    for (int ec = 0; ec < 2; ++ec) {
        float acc[8][8];
#pragma unroll
        for (int i = 0; i < 8; ++i)
#pragma unroll
            for (int j = 0; j < 8; ++j) acc[i][j] = 0.f;

        for (int kc = 0; kc < PD; kc += BKC) {
            __syncthreads();
            // stage A tile (transposed): As[k][m]
#pragma unroll
            for (int p = 0; p < 8; ++p) {
                const int r = r0 + p * 16;
                const float4 v = *(const float4*)&xs[(bm + r) * PD + kc + kq * 4];
                As[kq * 4 + 0][r] = v.x;
                As[kq * 4 + 1][r] = v.y;
                As[kq * 4 + 2][r] = v.z;
                As[kq * 4 + 3][r] = v.w;
            }
            // stage W tile (transposed): Ws[k][e_local]
#pragma unroll
            for (int p = 0; p < 8; ++p) {
                const int r = r0 + p * 16;
                const float4 v = *(const float4*)&W[(ec * 128 + r) * PD + kc + kq * 4];
                Ws[kq * 4 + 0][r] = v.x;
                Ws[kq * 4 + 1][r] = v.y;
                Ws[kq * 4 + 2][r] = v.z;
                Ws[kq * 4 + 3][r] = v.w;
            }
            __syncthreads();

#pragma unroll 8
            for (int k = 0; k < BKC; ++k) {
                const float4 a0 = *(const float4*)&As[k][ty * 8];
                const float4 a1 = *(const float4*)&As[k][ty * 8 + 4];
                const float4 w0 = *(const float4*)&Ws[k][tx * 8];
                const float4 w1 = *(const float4*)&Ws[k][tx * 8 + 4];
                const float a[8] = {a0.x, a0.y, a0.z, a0.w, a1.x, a1.y, a1.z, a1.w};
                const float w[8] = {w0.x, w0.y, w0.z, w0.w, w1.x, w1.y, w1.z, w1.w};
#pragma unroll
                for (int i = 0; i < 8; ++i)
#pragma unroll
                    for (int j = 0; j < 8; ++j)
                        acc[i][j] = fmaf(a[i], w[j], acc[i][j]);
            }
        }

        // epilogue: + bias, tanh, dot with attn over e
        float bv[8], av[8];
#pragma unroll
        for (int j = 0; j < 8; ++j) {
            const int e = ec * 128 + tx * 8 + j;
            bv[j] = bias[e];
            av[j] = attn[e];
        }
#pragma unroll
        for (int i = 0; i < 8; ++i) {
            float s = 0.f;
#pragma unroll
            for (int j = 0; j < 8; ++j) {
                const float u  = acc[i][j] + bv[j];
                const float e2 = __expf(2.f * u);           // inf for large u -> th=1
                const float th = 1.f - 2.f * __builtin_amdgcn_rcpf(e2 + 1.f);
                s = fmaf(th, av[j], s);
            }
            spart[i] += s;
        }
    }

    // reduce partial scores across the 16 tx threads sharing each row
    __syncthreads();
    float* sred = &As[0][0];         // 128*16 = 2048 floats, fits in As
#pragma unroll
    for (int i = 0; i < 8; ++i) sred[(ty * 8 + i) * 16 + tx] = spart[i];
    __syncthreads();
    if (tid < 128) {
        float s = 0.f;
#pragma unroll
        for (int q = 0; q < 16; ++q) s += sred[tid * 16 + q];
        scores[bm + tid] = s;
    }
}

// ---------------- Kernel B1: masked softmax over T, in place ---------------
__global__ __launch_bounds__(256) void softmax_kernel(
    const int* __restrict__ mask, float* __restrict__ sw)
{
    const int b   = blockIdx.x;
    const int tid = threadIdx.x;
    __shared__ float red[256];

    float s[8];
    int   v[8];
    float mx = -INFINITY;
#pragma unroll
    for (int i = 0; i < 8; ++i) {
        const int t = i * 256 + tid;
        s[i] = sw[b * PT + t];
        v[i] = mask[b * PT + t];
        if (v[i]) mx = fmaxf(mx, s[i]);
    }
    red[tid] = mx;
    __syncthreads();
    for (int st = 128; st > 0; st >>= 1) {
        if (tid < st) red[tid] = fmaxf(red[tid], red[tid + st]);
        __syncthreads();
    }
    mx = red[0];
    __syncthreads();

    float p[8];
    float ls = 0.f;
#pragma unroll
    for (int i = 0; i < 8; ++i) {
        p[i] = v[i] ? __expf(s[i] - mx) : 0.f;
        ls += p[i];
    }
    red[tid] = ls;
    __syncthreads();
    for (int st = 128; st > 0; st >>= 1) {
        if (tid < st) red[tid] += red[tid + st];
        __syncthreads();
    }
    const float inv = 1.f / red[0];
#pragma unroll
    for (int i = 0; i < 8; ++i) sw[b * PT + i * 256 + tid] = p[i] * inv;
}

// ---------------- Kernel B2: chunked weighted moments ----------------------
// grid (16 chunks, 64 batches); each block handles 128 t rows, writes a
// 512-float partial (mu[256], m2[256]) -- no atomics, fully overwritten.
__global__ __launch_bounds__(256) void moments_kernel(
    const float* __restrict__ xs, const float* __restrict__ w,
    float* __restrict__ part)
{
    const int chunk = blockIdx.x;     // 0..15
    const int b     = blockIdx.y;     // 0..63
    const int tid   = threadIdx.x;
    const int c     = tid & 63;       // float4 column (c*4 .. c*4+3)
    const int tq    = tid >> 6;       // 0..3, t sub-range

    __shared__ float  lw[128];
    __shared__ float4 rmu[4][64];
    __shared__ float4 rm2[4][64];

    if (tid < 128) lw[tid] = w[b * PT + chunk * 128 + tid];
    __syncthreads();

    float4 mu = {0.f, 0.f, 0.f, 0.f};
    float4 m2 = {0.f, 0.f, 0.f, 0.f};
    for (int i = 0; i < 32; ++i) {
        const int tl = tq * 32 + i;
        const float wv = lw[tl];
        const float4 x = *(const float4*)&xs[(b * PT + chunk * 128 + tl) * PD + c * 4];
        mu.x = fmaf(wv, x.x, mu.x); mu.y = fmaf(wv, x.y, mu.y);
        mu.z = fmaf(wv, x.z, mu.z); mu.w = fmaf(wv, x.w, mu.w);
        m2.x = fmaf(wv * x.x, x.x, m2.x); m2.y = fmaf(wv * x.y, x.y, m2.y);
        m2.z = fmaf(wv * x.z, x.z, m2.z); m2.w = fmaf(wv * x.w, x.w, m2.w);
    }
    rmu[tq][c] = mu;
    rm2[tq][c] = m2;
    __syncthreads();

    if (tid < 64) {
        float4 smu = rmu[0][tid], sm2 = rm2[0][tid];
        for (int q = 1; q < 4; ++q) {
            const float4 a = rmu[q][tid], d = rm2[q][tid];
            smu.x += a.x; smu.y += a.y; smu.z += a.z; smu.w += a.w;
            sm2.x += d.x; sm2.y += d.y; sm2.z += d.z; sm2.w += d.w;
        }
        const int base = (b * 16 + chunk) * 512;
        *(float4*)&part[base + tid * 4]       = smu;
        *(float4*)&part[base + 256 + tid * 4] = sm2;
    }
}

// ---------------- Kernel B3: reduce chunks, finalize mu / sqrt(var) --------
__global__ __launch_bounds__(256) void finalize_kernel(
    const float* __restrict__ part, float* __restrict__ out)
{
    const int b = blockIdx.x;
    const int d = threadIdx.x;
    float m1 = 0.f, m2 = 0.f;
#pragma unroll
    for (int ch = 0; ch < 16; ++ch) {
        const int base = (b * 16 + ch) * 512;
        m1 += part[base + d];
        m2 += part[base + 256 + d];
    }
    const float var = fmaxf(m2 - m1 * m1, 1e-5f);
    out[b * 512 + d]       = m1;
    out[b * 512 + 256 + d] = sqrtf(var);
}

extern "C" void kernel_launch(void* const* d_in, const int* in_sizes, int n_in,
                              void* d_out, int out_size, void* d_ws, size_t ws_size,
                              hipStream_t stream) {
    const float* xs   = (const float*)d_in[0];
    const int*   mask = (const int*)d_in[1];
    // d_in[2] = mask2, unused by the reference module
    const float* W    = (const float*)d_in[3];
    const float* bias = (const float*)d_in[4];
    const float* attn = (const float*)d_in[5];
    float* out = (float*)d_out;

    float* scores = (float*)d_ws;            // PB*PT floats; becomes w in place
    float* part   = scores + PB * PT;        // PB*16*512 floats

    score_kernel<<<PM / BM, 256, 0, stream>>>(xs, W, bias, attn, scores);
    softmax_kernel<<<PB, 256, 0, stream>>>(mask, scores);
    moments_kernel<<<dim3(16, PB), 256, 0, stream>>>(xs, scores, part);
    finalize_kernel<<<PB, 256, 0, stream>>>(part, out);
}

// Round 2
// 260.032 us; speedup vs baseline: 1.5723x; 1.5723x over previous
//
#include <hip/hip_runtime.h>
#include <hip/hip_bf16.h>
#include <math.h>

// Problem constants (reference: B=64, T=2048, D=256)
#define PB 64
#define PT 2048
#define PD 256
#define PM (PB * PT)

typedef __bf16 bf16x8 __attribute__((ext_vector_type(8)));
typedef short  s16x8  __attribute__((ext_vector_type(8)));
typedef float  f32x4  __attribute__((ext_vector_type(4)));

// split fp32 -> hi (truncated bf16) + lo (RNE bf16 of remainder)
__device__ __forceinline__ void split_bf16(float x, short& hi, short& lo) {
    unsigned u = __builtin_bit_cast(unsigned, x);
    hi = (short)(u >> 16);
    float hf = __builtin_bit_cast(float, u & 0xffff0000u);
    float r  = x - hf;
    unsigned v  = __builtin_bit_cast(unsigned, r);
    unsigned rb = v + 0x7fffu + ((v >> 16) & 1u);
    lo = (short)(rb >> 16);
}

// ---------------- Kernel P: pack W into hi/lo bf16 B-fragment order --------
// B[k][e] = W[e][k]. For mfma_f32_16x16x32_bf16, lane l holds
// B[k = (l>>4)*8 + j][n = l&15]. Packed flat index:
//   ((nt*8 + kt)*64 + quad*16 + n_loc)*8 + j
__global__ __launch_bounds__(256) void prep_kernel(
    const float* __restrict__ W, short* __restrict__ Whi, short* __restrict__ Wlo)
{
    const int idx = blockIdx.x * 256 + threadIdx.x;   // = e*256 + k
    const int e = idx >> 8;
    const int k = idx & 255;
    short h, l;
    split_bf16(W[idx], h, l);
    const int flat = (((e >> 4) * 8 + (k >> 5)) * 64 + ((k & 31) >> 3) * 16 + (e & 15)) * 8 + (k & 7);
    Whi[flat] = h;
    Wlo[flat] = l;
}

// ---------------- Kernel A: scores = attn . tanh(xs @ W^T + b) -------------
// MFMA 16x16x32 bf16, split hi/lo 3-pass. Block: 64 rows x 256 e, 4 waves,
// each wave owns a 64-col strip (4 ntiles) over full K=256 (8 ktiles).
#define SBM 64

__global__ __launch_bounds__(256, 2) void score_kernel(
    const float* __restrict__ xs, const short* __restrict__ Whi,
    const short* __restrict__ Wlo, const float* __restrict__ bias,
    const float* __restrict__ attn, float* __restrict__ scores)
{
    // A-fragment-packed LDS: [mt(4)][kt(8)][lane(64)][j(8)] shorts, XOR-swizzled
    __shared__ short Ahi[4 * 8 * 64 * 8];   // 32 KiB
    __shared__ short Alo[4 * 8 * 64 * 8];   // 32 KiB
    __shared__ float sred[4][64];

    const int tid = threadIdx.x;
    const int bm  = blockIdx.x * SBM;

    // ---- stage xs tile as split bf16 in A-fragment order ----
#pragma unroll
    for (int p = 0; p < 8; ++p) {
        const int r  = p * 8 + (tid >> 5);
        const int kb = tid & 31;                       // 8-elem k-block
        const float4 a0 = *(const float4*)&xs[(bm + r) * PD + kb * 8];
        const float4 a1 = *(const float4*)&xs[(bm + r) * PD + kb * 8 + 4];
        const float f[8] = {a0.x, a0.y, a0.z, a0.w, a1.x, a1.y, a1.z, a1.w};
        s16x8 h, l;
#pragma unroll
        for (int j = 0; j < 8; ++j) { short hh, ll; split_bf16(f[j], hh, ll); h[j] = hh; l[j] = ll; }
        const int mt = r >> 4, m_loc = r & 15;
        const int kt = kb >> 2, quad = kb & 3;
        const int msw = m_loc ^ (kb & 7);              // bank swizzle
        const int a_idx = (((mt * 8 + kt) * 64) + quad * 16 + msw) * 8;
        *(s16x8*)&Ahi[a_idx] = h;
        *(s16x8*)&Alo[a_idx] = l;
    }
    __syncthreads();

    const int lane = tid & 63;
    const int w    = tid >> 6;
    const int quad = lane >> 4;
    const int nl   = lane & 15;

    f32x4 acc[4][4] = {};   // [mtile][ntile_local]

#pragma unroll 2
    for (int kt = 0; kt < 8; ++kt) {
        bf16x8 bh[4], bl[4];
#pragma unroll
        for (int n = 0; n < 4; ++n) {
            const int nt = w * 4 + n;
            const int bidx = ((nt * 8 + kt) * 64 + lane) * 8;
            bh[n] = *(const bf16x8*)&Whi[bidx];
            bl[n] = *(const bf16x8*)&Wlo[bidx];
        }
        s16x8 ah[4], al[4];
        const int msw = nl ^ ((kt * 4 + quad) & 7);
#pragma unroll
        for (int m = 0; m < 4; ++m) {
            const int a_idx = ((m * 8 + kt) * 64 + quad * 16 + msw) * 8;
            ah[m] = *(const s16x8*)&Ahi[a_idx];
            al[m] = *(const s16x8*)&Alo[a_idx];
        }
#pragma unroll
        for (int m = 0; m < 4; ++m) {
            const bf16x8 ahm = __builtin_bit_cast(bf16x8, ah[m]);
            const bf16x8 alm = __builtin_bit_cast(bf16x8, al[m]);
#pragma unroll
            for (int n = 0; n < 4; ++n) {
                acc[m][n] = __builtin_amdgcn_mfma_f32_16x16x32_bf16(ahm, bh[n], acc[m][n], 0, 0, 0);
                acc[m][n] = __builtin_amdgcn_mfma_f32_16x16x32_bf16(ahm, bl[n], acc[m][n], 0, 0, 0);
                acc[m][n] = __builtin_amdgcn_mfma_f32_16x16x32_bf16(alm, bh[n], acc[m][n], 0, 0, 0);
            }
        }
    }

    // ---- epilogue: +bias, tanh, dot attn over e, reduce ----
#pragma unroll
    for (int m = 0; m < 4; ++m) {
        float rs[4] = {0.f, 0.f, 0.f, 0.f};
#pragma unroll
        for (int n = 0; n < 4; ++n) {
            const int col = w * 64 + n * 16 + nl;
            const float bv = bias[col];
            const float av = attn[col];
#pragma unroll
            for (int r = 0; r < 4; ++r) {
                const float u  = acc[m][n][r] + bv;
                const float e2 = __expf(2.f * u);                    // inf ok -> th=1
                const float th = 1.f - 2.f * __builtin_amdgcn_rcpf(e2 + 1.f);
                rs[r] = fmaf(th, av, rs[r]);
            }
        }
#pragma unroll
        for (int off = 1; off < 16; off <<= 1) {
#pragma unroll
            for (int r = 0; r < 4; ++r) rs[r] += __shfl_xor(rs[r], off);
        }
        if (nl == 0) {
#pragma unroll
            for (int r = 0; r < 4; ++r) sred[w][m * 16 + quad * 4 + r] = rs[r];
        }
    }
    __syncthreads();
    if (tid < 64)
        scores[bm + tid] = sred[0][tid] + sred[1][tid] + sred[2][tid] + sred[3][tid];
}

// ---------------- Kernel B1: masked softmax over T, in place ---------------
__global__ __launch_bounds__(256) void softmax_kernel(
    const int* __restrict__ mask, float* __restrict__ sw)
{
    const int b   = blockIdx.x;
    const int tid = threadIdx.x;
    __shared__ float red[256];

    float s[8];
    int   v[8];
    float mx = -INFINITY;
#pragma unroll
    for (int i = 0; i < 8; ++i) {
        const int t = i * 256 + tid;
        s[i] = sw[b * PT + t];
        v[i] = mask[b * PT + t];
        if (v[i]) mx = fmaxf(mx, s[i]);
    }
    red[tid] = mx;
    __syncthreads();
    for (int st = 128; st > 0; st >>= 1) {
        if (tid < st) red[tid] = fmaxf(red[tid], red[tid + st]);
        __syncthreads();
    }
    mx = red[0];
    __syncthreads();

    float p[8];
    float ls = 0.f;
#pragma unroll
    for (int i = 0; i < 8; ++i) {
        p[i] = v[i] ? __expf(s[i] - mx) : 0.f;
        ls += p[i];
    }
    red[tid] = ls;
    __syncthreads();
    for (int st = 128; st > 0; st >>= 1) {
        if (tid < st) red[tid] += red[tid + st];
        __syncthreads();
    }
    const float inv = 1.f / red[0];
#pragma unroll
    for (int i = 0; i < 8; ++i) sw[b * PT + i * 256 + tid] = p[i] * inv;
}

// ---------------- Kernel B2: chunked weighted moments ----------------------
__global__ __launch_bounds__(256) void moments_kernel(
    const float* __restrict__ xs, const float* __restrict__ w,
    float* __restrict__ part)
{
    const int chunk = blockIdx.x;     // 0..15
    const int b     = blockIdx.y;     // 0..63
    const int tid   = threadIdx.x;
    const int c     = tid & 63;       // float4 column
    const int tq    = tid >> 6;       // 0..3

    __shared__ float  lw[128];
    __shared__ float4 rmu[4][64];
    __shared__ float4 rm2[4][64];

    if (tid < 128) lw[tid] = w[b * PT + chunk * 128 + tid];
    __syncthreads();

    float4 mu = {0.f, 0.f, 0.f, 0.f};
    float4 m2 = {0.f, 0.f, 0.f, 0.f};
    for (int i = 0; i < 32; ++i) {
        const int tl = tq * 32 + i;
        const float wv = lw[tl];
        const float4 x = *(const float4*)&xs[(b * PT + chunk * 128 + tl) * PD + c * 4];
        mu.x = fmaf(wv, x.x, mu.x); mu.y = fmaf(wv, x.y, mu.y);
        mu.z = fmaf(wv, x.z, mu.z); mu.w = fmaf(wv, x.w, mu.w);
        m2.x = fmaf(wv * x.x, x.x, m2.x); m2.y = fmaf(wv * x.y, x.y, m2.y);
        m2.z = fmaf(wv * x.z, x.z, m2.z); m2.w = fmaf(wv * x.w, x.w, m2.w);
    }
    rmu[tq][c] = mu;
    rm2[tq][c] = m2;
    __syncthreads();

    if (tid < 64) {
        float4 smu = rmu[0][tid], sm2 = rm2[0][tid];
        for (int q = 1; q < 4; ++q) {
            const float4 a = rmu[q][tid], d = rm2[q][tid];
            smu.x += a.x; smu.y += a.y; smu.z += a.z; smu.w += a.w;
            sm2.x += d.x; sm2.y += d.y; sm2.z += d.z; sm2.w += d.w;
        }
        const int base = (b * 16 + chunk) * 512;
        *(float4*)&part[base + tid * 4]       = smu;
        *(float4*)&part[base + 256 + tid * 4] = sm2;
    }
}

// ---------------- Kernel B3: reduce chunks, finalize -----------------------
__global__ __launch_bounds__(256) void finalize_kernel(
    const float* __restrict__ part, float* __restrict__ out)
{
    const int b = blockIdx.x;
    const int d = threadIdx.x;
    float m1 = 0.f, m2 = 0.f;
#pragma unroll
    for (int ch = 0; ch < 16; ++ch) {
        const int base = (b * 16 + ch) * 512;
        m1 += part[base + d];
        m2 += part[base + 256 + d];
    }
    const float var = fmaxf(m2 - m1 * m1, 1e-5f);
    out[b * 512 + d]       = m1;
    out[b * 512 + 256 + d] = sqrtf(var);
}

extern "C" void kernel_launch(void* const* d_in, const int* in_sizes, int n_in,
                              void* d_out, int out_size, void* d_ws, size_t ws_size,
                              hipStream_t stream) {
    const float* xs   = (const float*)d_in[0];
    const int*   mask = (const int*)d_in[1];
    // d_in[2] = mask2, unused
    const float* W    = (const float*)d_in[3];
    const float* bias = (const float*)d_in[4];
    const float* attn = (const float*)d_in[5];
    float* out = (float*)d_out;

    float* scores = (float*)d_ws;                    // PB*PT floats
    float* part   = scores + PB * PT;                // PB*16*512 floats
    short* Whi    = (short*)(part + PB * 16 * 512);  // 65536 shorts
    short* Wlo    = Whi + PD * PD;                   // 65536 shorts

    prep_kernel<<<PD * PD / 256, 256, 0, stream>>>(W, Whi, Wlo);
    score_kernel<<<PM / SBM, 256, 0, stream>>>(xs, Whi, Wlo, bias, attn, scores);
    softmax_kernel<<<PB, 256, 0, stream>>>(mask, scores);
    moments_kernel<<<dim3(16, PB), 256, 0, stream>>>(xs, scores, part);
    finalize_kernel<<<PB, 256, 0, stream>>>(part, out);
}

// Round 3
// 252.346 us; speedup vs baseline: 1.6202x; 1.0305x over previous
//
#include <hip/hip_runtime.h>
#include <hip/hip_bf16.h>
#include <math.h>

// Problem constants (reference: B=64, T=2048, D=256)
#define PB 64
#define PT 2048
#define PD 256
#define PM (PB * PT)

typedef __bf16 bf16x8 __attribute__((ext_vector_type(8)));
typedef short  s16x8  __attribute__((ext_vector_type(8)));
typedef float  f32x4  __attribute__((ext_vector_type(4)));

__device__ __forceinline__ short rne_bf16(float x) {
    unsigned u = __builtin_bit_cast(unsigned, x);
    return (short)((u + 0x7fffu + ((u >> 16) & 1u)) >> 16);
}

// split fp32 -> hi (truncated bf16) + lo (RNE bf16 of remainder); hi+lo ~ 2^-17 accurate
__device__ __forceinline__ void split_bf16(float x, short& hi, short& lo) {
    unsigned u = __builtin_bit_cast(unsigned, x);
    hi = (short)(u >> 16);
    float hf = __builtin_bit_cast(float, u & 0xffff0000u);
    lo = rne_bf16(x - hf);
}

// ---------------- Kernel P: pack W into hi/lo bf16 B-fragment order --------
// B[k][e] = W[e][k]. mfma_f32_16x16x32_bf16: lane l holds B[k=(l>>4)*8+j][n=l&15].
// flat = ((nt*8 + kt)*64 + quad*16 + n_loc)*8 + j
__global__ __launch_bounds__(256) void prep_kernel(
    const float* __restrict__ W, short* __restrict__ Whi, short* __restrict__ Wlo)
{
    const int idx = blockIdx.x * 256 + threadIdx.x;   // = e*256 + k
    const int e = idx >> 8;
    const int k = idx & 255;
    short h, l;
    split_bf16(W[idx], h, l);
    const int flat = (((e >> 4) * 8 + (k >> 5)) * 64 + ((k & 31) >> 3) * 16 + (e & 15)) * 8 + (k & 7);
    Whi[flat] = h;
    Wlo[flat] = l;
}

// ---------------- Kernel A: scores = attn . tanh(xs @ W^T + b) -------------
// MFMA 16x16x32 bf16, 2-pass: xhi . (Whi + Wlo). Block: 64 rows x 256 e,
// 4 waves, each wave a 64-col strip (4 ntiles) over K=256 (8 ktiles).
// LDS 33 KiB -> 4 blocks/CU; launch_bounds(256,4) caps VGPR at 128.
#define SBM 64

__global__ __launch_bounds__(256, 4) void score_kernel(
    const float* __restrict__ xs, const short* __restrict__ Whi,
    const short* __restrict__ Wlo, const float* __restrict__ bias,
    const float* __restrict__ attn, float* __restrict__ scores)
{
    // A-fragment-packed LDS: [mt(4)][kt(8)][lane(64)][j(8)] shorts, XOR-swizzled
    __shared__ short Ah[4 * 8 * 64 * 8];    // 32 KiB
    __shared__ float sred[4][64];

    const int tid = threadIdx.x;
    const int bm  = blockIdx.x * SBM;

    // ---- stage xs tile as RNE bf16 in A-fragment order ----
#pragma unroll
    for (int p = 0; p < 8; ++p) {
        const int r  = p * 8 + (tid >> 5);
        const int kb = tid & 31;                       // 8-elem k-block
        const float4 a0 = *(const float4*)&xs[(bm + r) * PD + kb * 8];
        const float4 a1 = *(const float4*)&xs[(bm + r) * PD + kb * 8 + 4];
        const float f[8] = {a0.x, a0.y, a0.z, a0.w, a1.x, a1.y, a1.z, a1.w};
        s16x8 h;
#pragma unroll
        for (int j = 0; j < 8; ++j) h[j] = rne_bf16(f[j]);
        const int mt = r >> 4, m_loc = r & 15;
        const int kt = kb >> 2, quad = kb & 3;
        const int msw = m_loc ^ (kb & 7);              // bank swizzle
        *(s16x8*)&Ah[(((mt * 8 + kt) * 64) + quad * 16 + msw) * 8] = h;
    }
    __syncthreads();

    const int lane = tid & 63;
    const int w    = tid >> 6;
    const int quad = lane >> 4;
    const int nl   = lane & 15;

    f32x4 acc[4][4] = {};   // [mtile][ntile_local]

#pragma unroll 2
    for (int kt = 0; kt < 8; ++kt) {
        bf16x8 bh[4], bl[4];
#pragma unroll
        for (int n = 0; n < 4; ++n) {
            const int nt = w * 4 + n;
            const int bidx = ((nt * 8 + kt) * 64 + lane) * 8;
            bh[n] = *(const bf16x8*)&Whi[bidx];
            bl[n] = *(const bf16x8*)&Wlo[bidx];
        }
        s16x8 ah[4];
        const int msw = nl ^ ((kt * 4 + quad) & 7);
#pragma unroll
        for (int m = 0; m < 4; ++m)
            ah[m] = *(const s16x8*)&Ah[((m * 8 + kt) * 64 + quad * 16 + msw) * 8];
#pragma unroll
        for (int m = 0; m < 4; ++m) {
            const bf16x8 ahm = __builtin_bit_cast(bf16x8, ah[m]);
#pragma unroll
            for (int n = 0; n < 4; ++n) {
                acc[m][n] = __builtin_amdgcn_mfma_f32_16x16x32_bf16(ahm, bh[n], acc[m][n], 0, 0, 0);
                acc[m][n] = __builtin_amdgcn_mfma_f32_16x16x32_bf16(ahm, bl[n], acc[m][n], 0, 0, 0);
            }
        }
    }

    // ---- epilogue: +bias, tanh, dot attn over e, reduce ----
    float bv[4], av[4];
#pragma unroll
    for (int n = 0; n < 4; ++n) {
        const int col = w * 64 + n * 16 + nl;
        bv[n] = bias[col];
        av[n] = attn[col];
    }
#pragma unroll
    for (int m = 0; m < 4; ++m) {
        float rs[4] = {0.f, 0.f, 0.f, 0.f};
#pragma unroll
        for (int n = 0; n < 4; ++n) {
#pragma unroll
            for (int r = 0; r < 4; ++r) {
                const float u  = acc[m][n][r] + bv[n];
                const float e2 = __expf(2.f * u);                    // inf ok -> th=1
                const float th = 1.f - 2.f * __builtin_amdgcn_rcpf(e2 + 1.f);
                rs[r] = fmaf(th, av[n], rs[r]);
            }
        }
#pragma unroll
        for (int off = 1; off < 16; off <<= 1) {
#pragma unroll
            for (int r = 0; r < 4; ++r) rs[r] += __shfl_xor(rs[r], off);
        }
        if (nl == 0) {
#pragma unroll
            for (int r = 0; r < 4; ++r) sred[w][m * 16 + quad * 4 + r] = rs[r];
        }
    }
    __syncthreads();
    if (tid < 64)
        scores[bm + tid] = sred[0][tid] + sred[1][tid] + sred[2][tid] + sred[3][tid];
}

// ---------------- Kernel B1: masked softmax over T, in place ---------------
__global__ __launch_bounds__(256) void softmax_kernel(
    const int* __restrict__ mask, float* __restrict__ sw)
{
    const int b    = blockIdx.x;
    const int tid  = threadIdx.x;
    const int lane = tid & 63;
    const int wv   = tid >> 6;
    __shared__ float wred[4];

    float s[8];
    int   v[8];
    float mx = -INFINITY;
#pragma unroll
    for (int i = 0; i < 8; ++i) {
        const int t = i * 256 + tid;
        s[i] = sw[b * PT + t];
        v[i] = mask[b * PT + t];
        if (v[i]) mx = fmaxf(mx, s[i]);
    }
#pragma unroll
    for (int off = 1; off < 64; off <<= 1) mx = fmaxf(mx, __shfl_xor(mx, off));
    if (lane == 0) wred[wv] = mx;
    __syncthreads();
    mx = fmaxf(fmaxf(wred[0], wred[1]), fmaxf(wred[2], wred[3]));
    __syncthreads();

    float p[8];
    float ls = 0.f;
#pragma unroll
    for (int i = 0; i < 8; ++i) {
        p[i] = v[i] ? __expf(s[i] - mx) : 0.f;
        ls += p[i];
    }
#pragma unroll
    for (int off = 1; off < 64; off <<= 1) ls += __shfl_xor(ls, off);
    if (lane == 0) wred[wv] = ls;
    __syncthreads();
    const float inv = 1.f / (wred[0] + wred[1] + wred[2] + wred[3]);
#pragma unroll
    for (int i = 0; i < 8; ++i) sw[b * PT + i * 256 + tid] = p[i] * inv;
}

// ---------------- Kernel B2: chunked weighted moments ----------------------
__global__ __launch_bounds__(256) void moments_kernel(
    const float* __restrict__ xs, const float* __restrict__ w,
    float* __restrict__ part)
{
    const int chunk = blockIdx.x;     // 0..15
    const int b     = blockIdx.y;     // 0..63
    const int tid   = threadIdx.x;
    const int c     = tid & 63;       // float4 column
    const int tq    = tid >> 6;       // 0..3

    __shared__ float  lw[128];
    __shared__ float4 rmu[4][64];
    __shared__ float4 rm2[4][64];

    if (tid < 128) lw[tid] = w[b * PT + chunk * 128 + tid];
    __syncthreads();

    float4 mu = {0.f, 0.f, 0.f, 0.f};
    float4 m2 = {0.f, 0.f, 0.f, 0.f};
    for (int i = 0; i < 32; ++i) {
        const int tl = tq * 32 + i;
        const float wv = lw[tl];
        const float4 x = *(const float4*)&xs[(b * PT + chunk * 128 + tl) * PD + c * 4];
        mu.x = fmaf(wv, x.x, mu.x); mu.y = fmaf(wv, x.y, mu.y);
        mu.z = fmaf(wv, x.z, mu.z); mu.w = fmaf(wv, x.w, mu.w);
        m2.x = fmaf(wv * x.x, x.x, m2.x); m2.y = fmaf(wv * x.y, x.y, m2.y);
        m2.z = fmaf(wv * x.z, x.z, m2.z); m2.w = fmaf(wv * x.w, x.w, m2.w);
    }
    rmu[tq][c] = mu;
    rm2[tq][c] = m2;
    __syncthreads();

    if (tid < 64) {
        float4 smu = rmu[0][tid], sm2 = rm2[0][tid];
        for (int q = 1; q < 4; ++q) {
            const float4 a = rmu[q][tid], d = rm2[q][tid];
            smu.x += a.x; smu.y += a.y; smu.z += a.z; smu.w += a.w;
            sm2.x += d.x; sm2.y += d.y; sm2.z += d.z; sm2.w += d.w;
        }
        const int base = (b * 16 + chunk) * 512;
        *(float4*)&part[base + tid * 4]       = smu;
        *(float4*)&part[base + 256 + tid * 4] = sm2;
    }
}

// ---------------- Kernel B3: reduce chunks, finalize -----------------------
__global__ __launch_bounds__(256) void finalize_kernel(
    const float* __restrict__ part, float* __restrict__ out)
{
    const int b = blockIdx.x;
    const int d = threadIdx.x;
    float m1 = 0.f, m2 = 0.f;
#pragma unroll
    for (int ch = 0; ch < 16; ++ch) {
        const int base = (b * 16 + ch) * 512;
        m1 += part[base + d];
        m2 += part[base + 256 + d];
    }
    const float var = fmaxf(m2 - m1 * m1, 1e-5f);
    out[b * 512 + d]       = m1;
    out[b * 512 + 256 + d] = sqrtf(var);
}

extern "C" void kernel_launch(void* const* d_in, const int* in_sizes, int n_in,
                              void* d_out, int out_size, void* d_ws, size_t ws_size,
                              hipStream_t stream) {
    const float* xs   = (const float*)d_in[0];
    const int*   mask = (const int*)d_in[1];
    // d_in[2] = mask2, unused
    const float* W    = (const float*)d_in[3];
    const float* bias = (const float*)d_in[4];
    const float* attn = (const float*)d_in[5];
    float* out = (float*)d_out;

    float* scores = (float*)d_ws;                    // PB*PT floats
    float* part   = scores + PB * PT;                // PB*16*512 floats
    short* Whi    = (short*)(part + PB * 16 * 512);  // 65536 shorts
    short* Wlo    = Whi + PD * PD;                   // 65536 shorts

    prep_kernel<<<PD * PD / 256, 256, 0, stream>>>(W, Whi, Wlo);
    score_kernel<<<PM / SBM, 256, 0, stream>>>(xs, Whi, Wlo, bias, attn, scores);
    softmax_kernel<<<PB, 256, 0, stream>>>(mask, scores);
    moments_kernel<<<dim3(16, PB), 256, 0, stream>>>(xs, scores, part);
    finalize_kernel<<<PB, 256, 0, stream>>>(part, out);
}